// Round 6
// baseline (185.612 us; speedup 1.0000x reference)
//
#include <hip/hip_runtime.h>
#include <math.h>

// TrafficAugmentation R6. One block per row (S=4096), 512 threads, PER=8.
// vs R5: segment exit-compression (2a) + 9 swizzled doubling rounds + divergent
// mark expansion (2c) replaced by 12 LEAN position-level doubling rounds:
//  - cyclic ownership (thread t owns {t+512i}) -> plain u16 ping-pong jump
//    buffers, consecutive-lane writes (conflict-free, ZERO swizzle VALU);
//  - marks = 4096-bit LDS bitmask; invariant: after round k all chain nodes
//    within 2^(k+1)-1 hops of node 0 are marked; 2^12=4096 covers worst case;
//  - phase 3 reads its segment's mark byte directly (no divergent walk).
// LDS 25.2 KB -> 4 blocks/CU (wave-limited 100%).
// Exactness: serial fp32 r-=d[j] chain order preserved; burst sums serial
// increasing-j; rem = buf - nf*1448.0f exact (nf*1448 < 2^24).

#define S_LEN 4096
#define BLOCK 512
#define PER   8
#define MSSF  1448.0f

// LDS: region A (16416 B) = dly f32[4104] (ph0-1) / jA u16[4097]@0 +
//      jB u16[4097]@8200 (ph2) / out f32[4096] (ph4)
#define OFF_A    0
#define OFF_JB   8200
#define OFF_NXT  16416    // u16[4097], s2i-swizzled (blocked reads in ph3)
#define OFF_MRK  24612    // u32[128] bit-per-position marks
#define OFF_WS   25124    // i32[8]
#define SMEM_SZ  25160

// u16 swizzle for s_nxt only (blocked stride-8 reads in phase 3); cyclic
// phase-1 writes stay conflict-free under it (p^const within a wave).
__device__ __forceinline__ int s2i(int p) { return p ^ (((p >> 6) & 15) << 1); }

__global__ __launch_bounds__(BLOCK, 8) void traffic_kernel(
    const float* __restrict__ gx,
    const float* __restrict__ gd,
    const float* __restrict__ gr,
    float* __restrict__ gout)
{
    __shared__ __align__(16) unsigned char smem[SMEM_SZ];
    float*          s_dly = (float*)(smem + OFF_A);
    unsigned short* s_jA  = (unsigned short*)(smem + OFF_A);
    unsigned short* s_jB  = (unsigned short*)(smem + OFF_JB);
    float*          s_out = (float*)(smem + OFF_A);
    unsigned short* s_nxt = (unsigned short*)(smem + OFF_NXT);
    unsigned*       s_mrk = (unsigned*)(smem + OFF_MRK);
    int*            s_ws  = (int*)(smem + OFF_WS);

    const int tid = threadIdx.x;
    const size_t rowoff = (size_t)blockIdx.x * S_LEN;
    const float* px = gx + rowoff;
    const float* pd = gd + rowoff;
    const float* pr = gr + rowoff;

    // ---- Phase 0: stage delays (plain); pad +1e30 so windows past row end
    // self-terminate (delays > 0 keeps r strictly decreasing everywhere).
    {
        const float4* pd4 = (const float4*)pd;
        float4* s4 = (float4*)s_dly;
        for (int q = tid; q < S_LEN / 4; q += BLOCK) s4[q] = pd4[q];
        if (tid < 8) s_dly[S_LEN + tid] = 1.0e30f;
    }
    float rt[PER];
    unsigned alive = 0;
#pragma unroll
    for (int i = 0; i < PER; ++i) rt[i] = pr[tid + (i << 9)];
#pragma unroll
    for (int i = 0; i < PER; ++i) alive |= (px[tid + (i << 9)] > 0.0f) ? (1u << i) : 0u;
    __syncthreads();

    // ---- Phase 1 pass 1: all 8 first-windows (static addresses, ILP) ----
    unsigned surv = 0;
    float rsv[PER];
#pragma unroll
    for (int i = 0; i < PER; ++i) {
        const int p0 = tid + (i << 9);
        const float* dw = s_dly + p0;
        float d0 = dw[0], d1 = dw[1], d2 = dw[2], d3 = dw[3];
        float d4 = dw[4], d5 = dw[5], d6 = dw[6], d7 = dw[7];
        float r1 = rt[i] - d0;          // exact reference subtract order
        float r2 = r1 - d1;
        float r3 = r2 - d2;
        float r4 = r3 - d3;
        float r5 = r4 - d4;
        float r6 = r5 - d5;
        float r7 = r6 - d6;
        float r8 = r7 - d7;
        // r strictly decreasing: first k with r_k<=0  ==  #(r_k>0)+1
        int c = (r1 > 0.0f) + (r2 > 0.0f) + (r3 > 0.0f) + (r4 > 0.0f) +
                (r5 > 0.0f) + (r6 > 0.0f) + (r7 > 0.0f) + (r8 > 0.0f);
        rsv[i] = r8;
        bool al = (alive >> i) & 1u;
        if (al && c == 8) {
            surv |= 1u << i;            // nxt written in pass 2
        } else {
            int nx = al ? (p0 + c + 1) : S_LEN;
            if (nx > S_LEN) nx = S_LEN;
            s_nxt[s2i(p0)] = (unsigned short)nx;
        }
    }

    // ---- Phase 1 pass 2: survivors, per-lane flattened drain ----
    while (surv) {
        int i = __ffs(surv) - 1;
        surv &= surv - 1;
        float rr = rsv[0];
#pragma unroll
        for (int ii = 1; ii < PER; ++ii) rr = (i == ii) ? rsv[ii] : rr;
        int p0 = tid + (i << 9);
        int j = p0 + 8;                  // survivors have p0+8 <= S_LEN
        int nx;
        while (true) {
            float e0 = s_dly[j],     e1 = s_dly[j + 1];
            float e2 = s_dly[j + 2], e3 = s_dly[j + 3];
            float e4 = s_dly[j + 4], e5 = s_dly[j + 5];
            float e6 = s_dly[j + 6], e7 = s_dly[j + 7];
            float q1 = rr - e0;
            float q2 = q1 - e1;
            float q3 = q2 - e2;
            float q4 = q3 - e3;
            float q5 = q4 - e4;
            float q6 = q5 - e5;
            float q7 = q6 - e6;
            float q8 = q7 - e7;
            int c2 = (q1 > 0.0f) + (q2 > 0.0f) + (q3 > 0.0f) + (q4 > 0.0f) +
                     (q5 > 0.0f) + (q6 > 0.0f) + (q7 > 0.0f) + (q8 > 0.0f);
            if (c2 < 8) { nx = j + c2 + 1; break; }   // pad +1e30 forces c2<8 at end
            j += 8;
            rr = q8;
        }
        if (nx > S_LEN) nx = S_LEN;      // run-off-row semantics
        s_nxt[s2i(p0)] = (unsigned short)nx;
    }
    __syncthreads();                     // dly dead from here; region A -> jA/jB

    // ---- Phase 2 init: copy nxt -> jA (cyclic: conflict-free both sides),
    // own[] mirrors in registers; seed mark bit 0.
    int own[PER];
#pragma unroll
    for (int i = 0; i < PER; ++i) {
        int p = tid + (i << 9);
        int v = (int)s_nxt[s2i(p)];
        own[i] = v;
        s_jA[p] = (unsigned short)v;
    }
    if (tid == 0) { s_jA[4096] = (unsigned short)4096; s_jB[4096] = (unsigned short)4096; }
    if (tid < 128) s_mrk[tid] = (tid == 0) ? 1u : 0u;
    __syncthreads();

    // ---- Phase 2: 12 lean doubling rounds over positions (plain layout).
    // Round k: every marked node marks its 2^k-successor, then jump doubles.
    // Single barrier per round (reads hit ja, writes hit jb; mark races are
    // monotone-benign).
    {
        unsigned short* ja = s_jA;
        unsigned short* jb = s_jB;
        for (int k = 0; k < 12; ++k) {
#pragma unroll
            for (int i = 0; i < PER; ++i) {
                unsigned mw = s_mrk[(tid >> 5) + (i << 4)];
                if ((mw >> (tid & 31)) & 1u) {
                    int o = own[i];
                    if (o < S_LEN) atomicOr(&s_mrk[o >> 5], 1u << (o & 31));
                }
            }
            if (k < 11) {
                int nv[PER];
#pragma unroll
                for (int i = 0; i < PER; ++i) nv[i] = (int)ja[own[i]];
#pragma unroll
                for (int i = 0; i < PER; ++i) jb[tid + (i << 9)] = (unsigned short)nv[i];
#pragma unroll
                for (int i = 0; i < PER; ++i) own[i] = nv[i];
            }
            __syncthreads();
            unsigned short* t = ja; ja = jb; jb = t;
        }
    }

    // ---- Phase 3: burst sums for marked starts in own segment [8t, 8t+8)
    // (global x via L1), serial increasing-j adds; per-thread counts.
    const int sb = tid << 3;
    unsigned mbyte = (s_mrk[tid >> 2] >> ((tid & 3) << 3)) & 0xFFu;
    float bsum[PER];
    unsigned use = 0;
    int tsum = 0;
#pragma unroll
    for (int i = 0; i < PER; ++i) {
        float buf = 0.0f;
        int c = 0;
        if ((mbyte >> i) & 1u) {
            int p = sb + i;
            float xp = px[p];
            if (xp > 0.0f) {             // dead start (chain stops): no burst
                use |= 1u << i;
                int e = (int)s_nxt[s2i(p)];
                float sum = xp;
                for (int j = p + 1; j < e; ++j) sum += px[j];
                buf = sum;
                int nf = (int)ceilf(buf / MSSF) - 1; if (nf < 0) nf = 0;
                float rem = buf - (float)nf * MSSF;        // exact
                c = nf + (rem > 0.0f ? 1 : 0);
            }
        }
        bsum[i] = buf;
        tsum += c;
    }

    // ---- block exclusive scan of counts (8 waves) ----
    int texcl;
    {
        int lane = tid & 63, wv = tid >> 6;
        int v = tsum;
        for (int off = 1; off < 64; off <<= 1) {
            int u = __shfl_up(v, off, 64);
            if (lane >= off) v += u;
        }
        if (lane == 63) s_ws[wv] = v;
        __syncthreads();
        int woff = 0;
        for (int w = 0; w < wv; ++w) woff += s_ws[w];
        texcl = woff + v - tsum;
    }

    // ---- Phase 4: build output row in A (jump buffers dead), store ----
    {
        float4* z4 = (float4*)s_out;
        float4 zz; zz.x = zz.y = zz.z = zz.w = 0.0f;
        for (int q = tid; q < S_LEN / 4; q += BLOCK) z4[q] = zz;
    }
    __syncthreads();
    {
        int o = texcl;
#pragma unroll
        for (int i = 0; i < PER; ++i) {
            if ((use >> i) & 1u) {
                float buf = bsum[i];
                int nf = (int)ceilf(buf / MSSF) - 1; if (nf < 0) nf = 0;
                float rem = buf - (float)nf * MSSF;
                int e = o + nf; if (e > S_LEN) e = S_LEN;  // OOB drop == truncation
                for (int p2 = o; p2 < e; ++p2) s_out[p2] = MSSF;
                int rp = o + nf;
                if (rem > 0.0f && rp < S_LEN) s_out[rp] = rem;
                o += nf + (rem > 0.0f ? 1 : 0);
            }
        }
    }
    __syncthreads();
    {
        float4* po4 = (float4*)(gout + rowoff);
        float4* so4 = (float4*)s_out;
        for (int q = tid; q < S_LEN / 4; q += BLOCK) po4[q] = so4[q];
    }
}

extern "C" void kernel_launch(void* const* d_in, const int* in_sizes, int n_in,
                              void* d_out, int out_size, void* d_ws, size_t ws_size,
                              hipStream_t stream) {
    const float* x      = (const float*)d_in[0];
    const float* delays = (const float*)d_in[1];
    const float* rtts   = (const float*)d_in[2];
    float* out = (float*)d_out;
    int rows = in_sizes[0] / S_LEN;   // B = 2048
    traffic_kernel<<<rows, BLOCK, 0, stream>>>(x, delays, rtts, out);
}

// Round 7
// 174.079 us; speedup vs baseline: 1.0663x; 1.0663x over previous
//
#include <hip/hip_runtime.h>
#include <math.h>

// TrafficAugmentation R7. One block per row (S=4096), 512 threads, PER=8.
// vs R5 (best, 84us): doubling de-fatted, phase 4 branchless.
//  - 2a: fold in registers (no LDS dependent chain), single ds_write_b128 of
//    8 packed u16 jumps into a PLAIN jump table.
//  - 2b: 9 rounds; cyclic update-ownership (plain consecutive-lane writes,
//    plain random gathers, zero swizzle VALU); marks = u16 entry+1 per seg,
//    1 read + <=1 gather + <=1 write per thread per round. Races benign
//    (chain visits each segment at most once -> unique value).
//  - Phase 4: difference-array + block scan (branchless cover writeback)
//    instead of divergent per-burst fills; rem scattered after.
// Exactness: serial fp32 r-=d[j] chain order preserved; burst sums serial
// increasing-j; rem = buf - nf*1448.0f exact (nf*1448 < 2^24).

#define S_LEN 4096
#define BLOCK 512
#define PER   8
#define MSSF  1448.0f

// LDS region A (16416 B), sequential overlays:
//   dly f32[4104] (ph0-1) -> jmpA u16[4104]@0 + jmpB u16[4104]@8208 (ph2)
//   -> diff i32[4096] (ph4b) -> out f32[4096] (ph4c-e)
#define OFF_A    0
#define OFF_JB   8208
#define OFF_NXT  16416    // u16[4100], s2i-swizzled
#define OFF_MENT 24616    // u16[512]: chain entry+1 per segment (0 = unmarked)
#define OFF_WS   25640    // i32[8]
#define SMEM_SZ  25672

// u16 swizzle for s_nxt only: conflict-free for both cyclic writes (ph1) and
// blocked stride-8 reads (ph2a/2c); bijective on [0,4096).
__device__ __forceinline__ int s2i(int p) { return p ^ (((p >> 6) & 15) << 1); }

__global__ __launch_bounds__(BLOCK, 8) void traffic_kernel(
    const float* __restrict__ gx,
    const float* __restrict__ gd,
    const float* __restrict__ gr,
    float* __restrict__ gout)
{
    __shared__ __align__(16) unsigned char smem[SMEM_SZ];
    float*          s_dly  = (float*)(smem + OFF_A);
    unsigned short* s_jA   = (unsigned short*)(smem + OFF_A);
    unsigned short* s_jB   = (unsigned short*)(smem + OFF_JB);
    int*            s_diff = (int*)(smem + OFF_A);
    float*          s_out  = (float*)(smem + OFF_A);
    unsigned short* s_nxt  = (unsigned short*)(smem + OFF_NXT);
    unsigned short* s_ment = (unsigned short*)(smem + OFF_MENT);
    int*            s_ws   = (int*)(smem + OFF_WS);

    const int tid = threadIdx.x;
    const size_t rowoff = (size_t)blockIdx.x * S_LEN;
    const float* px = gx + rowoff;
    const float* pd = gd + rowoff;
    const float* pr = gr + rowoff;

    // ---- Phase 0: stage delays (plain); pad +1e30 so windows past row end
    // self-terminate (delays > 0 keeps r strictly decreasing everywhere).
    {
        const float4* pd4 = (const float4*)pd;
        float4* s4 = (float4*)s_dly;
        for (int q = tid; q < S_LEN / 4; q += BLOCK) s4[q] = pd4[q];
        if (tid < 8) s_dly[S_LEN + tid] = 1.0e30f;
    }
    float rt[PER];
    unsigned alive = 0;
#pragma unroll
    for (int i = 0; i < PER; ++i) rt[i] = pr[tid + (i << 9)];
#pragma unroll
    for (int i = 0; i < PER; ++i) alive |= (px[tid + (i << 9)] > 0.0f) ? (1u << i) : 0u;
    __syncthreads();

    // ---- Phase 1 pass 1: all 8 first-windows (static addresses, ILP) ----
    unsigned surv = 0;
    float rsv[PER];
#pragma unroll
    for (int i = 0; i < PER; ++i) {
        const int p0 = tid + (i << 9);
        const float* dw = s_dly + p0;
        float d0 = dw[0], d1 = dw[1], d2 = dw[2], d3 = dw[3];
        float d4 = dw[4], d5 = dw[5], d6 = dw[6], d7 = dw[7];
        float r1 = rt[i] - d0;          // exact reference subtract order
        float r2 = r1 - d1;
        float r3 = r2 - d2;
        float r4 = r3 - d3;
        float r5 = r4 - d4;
        float r6 = r5 - d5;
        float r7 = r6 - d6;
        float r8 = r7 - d7;
        // r strictly decreasing: first k with r_k<=0  ==  #(r_k>0)+1
        int c = (r1 > 0.0f) + (r2 > 0.0f) + (r3 > 0.0f) + (r4 > 0.0f) +
                (r5 > 0.0f) + (r6 > 0.0f) + (r7 > 0.0f) + (r8 > 0.0f);
        rsv[i] = r8;
        bool al = (alive >> i) & 1u;
        if (al && c == 8) {
            surv |= 1u << i;            // nxt written in pass 2
        } else {
            int nx = al ? (p0 + c + 1) : S_LEN;
            if (nx > S_LEN) nx = S_LEN;
            s_nxt[s2i(p0)] = (unsigned short)nx;
        }
    }

    // ---- Phase 1 pass 2: survivors, per-lane flattened drain ----
    while (surv) {
        int i = __ffs(surv) - 1;
        surv &= surv - 1;
        float rr = rsv[0];
#pragma unroll
        for (int ii = 1; ii < PER; ++ii) rr = (i == ii) ? rsv[ii] : rr;
        int p0 = tid + (i << 9);
        int j = p0 + 8;
        int nx;
        while (true) {
            float e0 = s_dly[j],     e1 = s_dly[j + 1];
            float e2 = s_dly[j + 2], e3 = s_dly[j + 3];
            float e4 = s_dly[j + 4], e5 = s_dly[j + 5];
            float e6 = s_dly[j + 6], e7 = s_dly[j + 7];
            float q1 = rr - e0;
            float q2 = q1 - e1;
            float q3 = q2 - e2;
            float q4 = q3 - e3;
            float q5 = q4 - e4;
            float q6 = q5 - e5;
            float q7 = q6 - e6;
            float q8 = q7 - e7;
            int c2 = (q1 > 0.0f) + (q2 > 0.0f) + (q3 > 0.0f) + (q4 > 0.0f) +
                     (q5 > 0.0f) + (q6 > 0.0f) + (q7 > 0.0f) + (q8 > 0.0f);
            if (c2 < 8) { nx = j + c2 + 1; break; }   // +1e30 pad forces exit
            j += 8;
            rr = q8;
        }
        if (nx > S_LEN) nx = S_LEN;
        s_nxt[s2i(p0)] = (unsigned short)nx;
    }
    __syncthreads();                     // dly dead; region A -> jmpA/jmpB

    // ---- Phase 2a: register fold -> jmp8 (first hop leaving own 8-seg),
    // one packed b128 write into PLAIN table.
    const int sb = tid << 3;
    {
        int nv[PER], ee[PER];
#pragma unroll
        for (int i = 0; i < PER; ++i) nv[i] = (int)s_nxt[s2i(sb + i)];
#pragma unroll
        for (int i = PER - 1; i >= 0; --i) {
            int v = nv[i];                 // v > sb+i
            int e = v;
#pragma unroll
            for (int j2 = i + 1; j2 < PER; ++j2)
                if (v == sb + j2) e = ee[j2];
            ee[i] = e;
        }
        uint4 pk;
        pk.x = (unsigned)ee[0] | ((unsigned)ee[1] << 16);
        pk.y = (unsigned)ee[2] | ((unsigned)ee[3] << 16);
        pk.z = (unsigned)ee[4] | ((unsigned)ee[5] << 16);
        pk.w = (unsigned)ee[6] | ((unsigned)ee[7] << 16);
        *(uint4*)&s_jA[sb] = pk;           // sb*2 bytes: 16B-aligned
    }
    if (tid == 0) { s_jA[4096] = (unsigned short)4096; s_jB[4096] = (unsigned short)4096; }
    s_ment[tid] = (tid == 0) ? (unsigned short)1 : (unsigned short)0;
    __syncthreads();

    // ---- Phase 2b: 9 doubling rounds over the seg-entry chain (<=512 nodes,
    // <=1 per segment: jmp8 hops strictly leave the segment). Cyclic update
    // ownership: plain conflict-free writes; plain random gathers. Marks:
    // after round k, all entries within 2^(k+1)-1 hops of node 0 are marked;
    // 2^9-1 = 511 covers the worst case.
    {
        unsigned short* ja = s_jA;
        unsigned short* jb = s_jB;
        int own[PER];
#pragma unroll
        for (int i = 0; i < PER; ++i) own[i] = (int)ja[tid + (i << 9)];
        for (int k = 0; k < 9; ++k) {
            int ent = (int)s_ment[tid];
            int q = -1;
            if (ent) {
                int e = (int)ja[ent - 1];
                if (e < S_LEN) q = e;
            }
            if (k < 8) {
                int nv[PER];
#pragma unroll
                for (int i = 0; i < PER; ++i) nv[i] = (int)ja[own[i]];
                if (q >= 0) s_ment[q >> 3] = (unsigned short)(q + 1);  // unique value: race benign
#pragma unroll
                for (int i = 0; i < PER; ++i) jb[tid + (i << 9)] = (unsigned short)nv[i];
#pragma unroll
                for (int i = 0; i < PER; ++i) own[i] = nv[i];
            } else {
                if (q >= 0) s_ment[q >> 3] = (unsigned short)(q + 1);
            }
            __syncthreads();
            unsigned short* t = ja; ja = jb; jb = t;
        }
    }

    // ---- Phase 2c: expand entry mark to chain nodes within own segment ----
    unsigned lm = 0;
    {
        int ent = (int)s_ment[tid];
        if (ent) {
            int p = ent - 1;
            while (p < sb + PER) {
                lm |= 1u << (p - sb);
                p = (int)s_nxt[s2i(p)];    // dead node -> 4096 -> exit
            }
        }
    }

    // ---- Phase 3: burst sums (global x via L1), serial increasing-j ----
    float bsum[PER];
    unsigned use = 0;
    int tsum = 0;
#pragma unroll
    for (int i = 0; i < PER; ++i) {
        float buf = 0.0f;
        int c = 0;
        if ((lm >> i) & 1u) {
            int p = sb + i;
            float xp = px[p];
            if (xp > 0.0f) {               // dead start: chain stops, no burst
                use |= 1u << i;
                int e = (int)s_nxt[s2i(p)];
                float sum = xp;
                for (int j = p + 1; j < e; ++j) sum += px[j];
                buf = sum;
                int nf = (int)ceilf(buf / MSSF) - 1; if (nf < 0) nf = 0;
                float rem = buf - (float)nf * MSSF;    // exact
                c = nf + (rem > 0.0f ? 1 : 0);
            }
        }
        bsum[i] = buf;
        tsum += c;
    }

    // ---- block exclusive scan of counts (8 waves) ----
    int texcl;
    {
        int lane = tid & 63, wv = tid >> 6;
        int v = tsum;
        for (int off = 1; off < 64; off <<= 1) {
            int u = __shfl_up(v, off, 64);
            if (lane >= off) v += u;
        }
        if (lane == 63) s_ws[wv] = v;
        __syncthreads();                   // also: jump tables dead after this
        int woff = 0;
        for (int w = 0; w < wv; ++w) woff += s_ws[w];
        texcl = woff + v - tsum;
    }

    // ---- Phase 4a: zero diff (region A; cyclic int4, conflict-free) ----
    {
        int4* d4 = (int4*)s_diff;
        int4 z; z.x = z.y = z.z = z.w = 0;
        d4[tid] = z;
        d4[tid + 512] = z;
    }
    __syncthreads();

    // ---- Phase 4b: difference-array scatter (+1 at start, -1 at end) ----
    {
        int o = texcl;
#pragma unroll
        for (int i = 0; i < PER; ++i) {
            if ((use >> i) & 1u) {
                float buf = bsum[i];
                int nf = (int)ceilf(buf / MSSF) - 1; if (nf < 0) nf = 0;
                float rem = buf - (float)nf * MSSF;
                if (nf > 0) {
                    if (o < S_LEN) atomicAdd(&s_diff[o], 1);
                    int e2 = o + nf;
                    if (e2 < S_LEN) atomicAdd(&s_diff[e2], -1);  // OOB drop
                }
                o += nf + (rem > 0.0f ? 1 : 0);
            }
        }
    }
    __syncthreads();

    // ---- Phase 4c: block-wide inclusive scan of diff -> cover writeback ----
    {
        int4 a = *(int4*)&s_diff[sb];
        int4 b = *(int4*)&s_diff[sb + 4];
        int v0 = a.x,      v1 = v0 + a.y, v2 = v1 + a.z, v3 = v2 + a.w;
        int v4 = v3 + b.x, v5 = v4 + b.y, v6 = v5 + b.z, v7 = v6 + b.w;
        int T = v7;
        int lane = tid & 63, wv = tid >> 6;
        int sc = T;
        for (int off = 1; off < 64; off <<= 1) {
            int u = __shfl_up(sc, off, 64);
            if (lane >= off) sc += u;
        }
        if (lane == 63) s_ws[wv] = sc;
        __syncthreads();
        int basev = 0;
        for (int w = 0; w < wv; ++w) basev += s_ws[w];
        basev += sc - T;                   // exclusive prefix for slot sb
        float4 fa, fb;
        fa.x = (basev + v0 > 0) ? MSSF : 0.0f;
        fa.y = (basev + v1 > 0) ? MSSF : 0.0f;
        fa.z = (basev + v2 > 0) ? MSSF : 0.0f;
        fa.w = (basev + v3 > 0) ? MSSF : 0.0f;
        fb.x = (basev + v4 > 0) ? MSSF : 0.0f;
        fb.y = (basev + v5 > 0) ? MSSF : 0.0f;
        fb.z = (basev + v6 > 0) ? MSSF : 0.0f;
        fb.w = (basev + v7 > 0) ? MSSF : 0.0f;
        *(float4*)&s_out[sb]     = fa;     // in-place over own diff slots: safe
        *(float4*)&s_out[sb + 4] = fb;
    }
    __syncthreads();

    // ---- Phase 4d: remainder scatter (rem slot is never MSS-covered) ----
    {
        int o = texcl;
#pragma unroll
        for (int i = 0; i < PER; ++i) {
            if ((use >> i) & 1u) {
                float buf = bsum[i];
                int nf = (int)ceilf(buf / MSSF) - 1; if (nf < 0) nf = 0;
                float rem = buf - (float)nf * MSSF;
                int rp = o + nf;
                if (rem > 0.0f && rp < S_LEN) s_out[rp] = rem;
                o += nf + (rem > 0.0f ? 1 : 0);
            }
        }
    }
    __syncthreads();

    // ---- Phase 4e: coalesced store ----
    {
        float4* po4 = (float4*)(gout + rowoff);
        const float4* so4 = (const float4*)s_out;
        po4[tid]       = so4[tid];
        po4[tid + 512] = so4[tid + 512];
    }
}

extern "C" void kernel_launch(void* const* d_in, const int* in_sizes, int n_in,
                              void* d_out, int out_size, void* d_ws, size_t ws_size,
                              hipStream_t stream) {
    const float* x      = (const float*)d_in[0];
    const float* delays = (const float*)d_in[1];
    const float* rtts   = (const float*)d_in[2];
    float* out = (float*)d_out;
    int rows = in_sizes[0] / S_LEN;   // B = 2048
    traffic_kernel<<<rows, BLOCK, 0, stream>>>(x, delays, rtts, out);
}

// Round 8
// 172.713 us; speedup vs baseline: 1.0747x; 1.0079x over previous
//
#include <hip/hip_runtime.h>
#include <math.h>

// TrafficAugmentation R8. One block per row (S=4096), 512 threads, PER=8.
// vs R7: segment-local serial work moved LDS -> registers.
//  - s_nxt PLAIN; own segment's 8 nxt read as ONE ds_read_b128 (conflict-free).
//  - dead-start patch in 2a registers (phase 1 uniform, no alive reads).
//  - 2c chain expansion = u64 nibble automaton in registers (no LDS chase).
//  - phase 3: own-segment x prefetched to registers (coalesced float4 x2);
//    predicated register adds (+0.0f exact for positives, order preserved);
//    only cross-segment tails read global.
// Exactness: serial fp32 r-=d[j] chain order; burst sums serial increasing-j;
// rem = buf - nf*1448.0f exact (nf*1448 < 2^24).

#define S_LEN 4096
#define BLOCK 512
#define PER   8
#define MSSF  1448.0f

// LDS region A (16416 B), sequential overlays:
//   dly f32[4104] (ph0-1) -> jmpA u16[4104]@0 + jmpB u16[4104]@8208 (ph2)
//   -> diff i32[4096] -> out f32[4096] (ph4)
#define OFF_A    0
#define OFF_JB   8208
#define OFF_NXT  16416    // u16[4104] PLAIN
#define OFF_MENT 24624    // u16[512]: chain entry+1 per segment (0 = unmarked)
#define OFF_WS   25648    // i32[8]
#define SMEM_SZ  25680

__global__ __launch_bounds__(BLOCK, 8) void traffic_kernel(
    const float* __restrict__ gx,
    const float* __restrict__ gd,
    const float* __restrict__ gr,
    float* __restrict__ gout)
{
    __shared__ __align__(16) unsigned char smem[SMEM_SZ];
    float*          s_dly  = (float*)(smem + OFF_A);
    unsigned short* s_jA   = (unsigned short*)(smem + OFF_A);
    unsigned short* s_jB   = (unsigned short*)(smem + OFF_JB);
    int*            s_diff = (int*)(smem + OFF_A);
    float*          s_out  = (float*)(smem + OFF_A);
    unsigned short* s_nxt  = (unsigned short*)(smem + OFF_NXT);
    unsigned short* s_ment = (unsigned short*)(smem + OFF_MENT);
    int*            s_ws   = (int*)(smem + OFF_WS);

    const int tid = threadIdx.x;
    const int sb  = tid << 3;
    const size_t rowoff = (size_t)blockIdx.x * S_LEN;
    const float* px = gx + rowoff;
    const float* pd = gd + rowoff;
    const float* pr = gr + rowoff;

    // ---- Phase 0: stage delays (plain); pad +1e30 (delays > 0 => r strictly
    // decreasing; windows past row end self-terminate). Prefetch own-segment
    // x (blocked, coalesced) and cyclic rtts.
    float xreg[PER];
    {
        float4 xa = *(const float4*)(px + sb);
        float4 xb = *(const float4*)(px + sb + 4);
        xreg[0]=xa.x; xreg[1]=xa.y; xreg[2]=xa.z; xreg[3]=xa.w;
        xreg[4]=xb.x; xreg[5]=xb.y; xreg[6]=xb.z; xreg[7]=xb.w;
    }
    {
        const float4* pd4 = (const float4*)pd;
        float4* s4 = (float4*)s_dly;
        for (int q = tid; q < S_LEN / 4; q += BLOCK) s4[q] = pd4[q];
        if (tid < 8) s_dly[S_LEN + tid] = 1.0e30f;
    }
    float rt[PER];
#pragma unroll
    for (int i = 0; i < PER; ++i) rt[i] = pr[tid + (i << 9)];
    __syncthreads();

    // ---- Phase 1 pass 1: all 8 first-windows (static addresses, ILP) ----
    unsigned surv = 0;
    float rsv[PER];
#pragma unroll
    for (int i = 0; i < PER; ++i) {
        const int p0 = tid + (i << 9);
        const float* dw = s_dly + p0;
        float d0 = dw[0], d1 = dw[1], d2 = dw[2], d3 = dw[3];
        float d4 = dw[4], d5 = dw[5], d6 = dw[6], d7 = dw[7];
        float r1 = rt[i] - d0;          // exact reference subtract order
        float r2 = r1 - d1;
        float r3 = r2 - d2;
        float r4 = r3 - d3;
        float r5 = r4 - d4;
        float r6 = r5 - d5;
        float r7 = r6 - d6;
        float r8 = r7 - d7;
        // r strictly decreasing: first k with r_k<=0  ==  #(r_k>0)+1
        int c = (r1 > 0.0f) + (r2 > 0.0f) + (r3 > 0.0f) + (r4 > 0.0f) +
                (r5 > 0.0f) + (r6 > 0.0f) + (r7 > 0.0f) + (r8 > 0.0f);
        rsv[i] = r8;
        if (c == 8) {
            surv |= 1u << i;            // nxt written in pass 2
        } else {
            int nx = p0 + c + 1;
            if (nx > S_LEN) nx = S_LEN;
            s_nxt[p0] = (unsigned short)nx;
        }
    }

    // ---- Phase 1 pass 2: survivors, per-lane flattened drain ----
    while (surv) {
        int i = __ffs(surv) - 1;
        surv &= surv - 1;
        float rr = rsv[0];
#pragma unroll
        for (int ii = 1; ii < PER; ++ii) rr = (i == ii) ? rsv[ii] : rr;
        int p0 = tid + (i << 9);
        int j = p0 + 8;
        int nx;
        while (true) {
            float e0 = s_dly[j],     e1 = s_dly[j + 1];
            float e2 = s_dly[j + 2], e3 = s_dly[j + 3];
            float e4 = s_dly[j + 4], e5 = s_dly[j + 5];
            float e6 = s_dly[j + 6], e7 = s_dly[j + 7];
            float q1 = rr - e0;
            float q2 = q1 - e1;
            float q3 = q2 - e2;
            float q4 = q3 - e3;
            float q5 = q4 - e4;
            float q6 = q5 - e5;
            float q7 = q6 - e6;
            float q8 = q7 - e7;
            int c2 = (q1 > 0.0f) + (q2 > 0.0f) + (q3 > 0.0f) + (q4 > 0.0f) +
                     (q5 > 0.0f) + (q6 > 0.0f) + (q7 > 0.0f) + (q8 > 0.0f);
            if (c2 < 8) { nx = j + c2 + 1; break; }   // +1e30 pad forces exit
            j += 8;
            rr = q8;
        }
        if (nx > S_LEN) nx = S_LEN;
        s_nxt[p0] = (unsigned short)nx;
    }
    __syncthreads();                     // dly dead; region A -> jmpA/jmpB

    // ---- Phase 2a: ONE b128 read of own segment's nxt; dead-start patch;
    // register fold -> jmp8; packed b128 write; build nibble automaton.
    int nx8[PER];
    unsigned long long rel = 0x8ull << 32;   // nibble 8 self-loops
    {
        uint4 ld = *(const uint4*)&s_nxt[sb];     // plain, conflict-free
        nx8[0] = ld.x & 0xFFFF; nx8[1] = ld.x >> 16;
        nx8[2] = ld.y & 0xFFFF; nx8[3] = ld.y >> 16;
        nx8[4] = ld.z & 0xFFFF; nx8[5] = ld.z >> 16;
        nx8[6] = ld.w & 0xFFFF; nx8[7] = ld.w >> 16;
#pragma unroll
        for (int i = 0; i < PER; ++i)
            if (!(xreg[i] > 0.0f)) nx8[i] = S_LEN;     // dead start: chain stops
        int ee[PER];
#pragma unroll
        for (int i = PER - 1; i >= 0; --i) {
            int v = nx8[i];                 // v > sb+i
            int e = v;
#pragma unroll
            for (int j2 = i + 1; j2 < PER; ++j2)
                if (v == sb + j2) e = ee[j2];
            ee[i] = e;
        }
        uint4 pk;
        pk.x = (unsigned)ee[0] | ((unsigned)ee[1] << 16);
        pk.y = (unsigned)ee[2] | ((unsigned)ee[3] << 16);
        pk.z = (unsigned)ee[4] | ((unsigned)ee[5] << 16);
        pk.w = (unsigned)ee[6] | ((unsigned)ee[7] << 16);
        *(uint4*)&s_jA[sb] = pk;            // byte offset 16*tid: aligned
#pragma unroll
        for (int i = 0; i < PER; ++i) {
            int r = nx8[i] - sb; if (r > 8) r = 8;     // in [1,8]
            rel |= (unsigned long long)r << (i << 2);
        }
    }
    if (tid == 0) { s_jA[4096] = (unsigned short)4096; s_jB[4096] = (unsigned short)4096; }
    s_ment[tid] = (tid == 0) ? (unsigned short)1 : (unsigned short)0;
    __syncthreads();

    // ---- Phase 2b: 9 doubling rounds over the seg-entry chain (<=512 nodes,
    // <=1 per segment). Cyclic update ownership: plain conflict-free writes,
    // plain random gathers. Mark value unique per segment -> races benign.
    {
        unsigned short* ja = s_jA;
        unsigned short* jb = s_jB;
        int own[PER];
#pragma unroll
        for (int i = 0; i < PER; ++i) own[i] = (int)ja[tid + (i << 9)];
        for (int k = 0; k < 9; ++k) {
            int ent = (int)s_ment[tid];
            int q = -1;
            if (ent) {
                int e = (int)ja[ent - 1];
                if (e < S_LEN) q = e;
            }
            if (k < 8) {
                int nv[PER];
#pragma unroll
                for (int i = 0; i < PER; ++i) nv[i] = (int)ja[own[i]];
                if (q >= 0) s_ment[q >> 3] = (unsigned short)(q + 1);
#pragma unroll
                for (int i = 0; i < PER; ++i) jb[tid + (i << 9)] = (unsigned short)nv[i];
#pragma unroll
                for (int i = 0; i < PER; ++i) own[i] = nv[i];
            } else {
                if (q >= 0) s_ment[q >> 3] = (unsigned short)(q + 1);
            }
            __syncthreads();
            unsigned short* t = ja; ja = jb; jb = t;
        }
    }

    // ---- Phase 2c: expand entry mark via register nibble automaton ----
    unsigned lm = 0;
    {
        int ent = (int)s_ment[tid];
        if (ent) {
            int p = ent - 1 - sb;            // 0..7 (entry is in own segment)
#pragma unroll
            for (int s = 0; s < PER; ++s) {
                lm |= (p < 8) ? (1u << p) : 0u;
                p = (int)((rel >> (p << 2)) & 15ull);   // nibble 8 -> 8 forever
            }
        }
    }

    // ---- Phase 3: burst sums. Own-segment part from registers (predicated
    // +0.0f adds: exact for positive values, serial order kept); cross-
    // segment tail from global. e from registers.
    float bsum[PER];
    unsigned use = 0;
    int tsum = 0;
#pragma unroll
    for (int i = 0; i < PER; ++i) {
        float buf = 0.0f;
        int c = 0;
        if ((lm >> i) & 1u) {
            float xp = xreg[i];
            if (xp > 0.0f) {               // dead start: chain stops, no burst
                use |= 1u << i;
                int e = nx8[i];
                int upper = e - sb;        // > i
                float sum = xp;
#pragma unroll
                for (int jj = i + 1; jj < PER; ++jj)
                    sum += (jj < upper) ? xreg[jj] : 0.0f;
                for (int j = sb + PER; j < e; ++j) sum += px[j];
                buf = sum;
                int nf = (int)ceilf(buf / MSSF) - 1; if (nf < 0) nf = 0;
                float rem = buf - (float)nf * MSSF;    // exact
                c = nf + (rem > 0.0f ? 1 : 0);
            }
        }
        bsum[i] = buf;
        tsum += c;
    }

    // ---- zero diff region (region A free after 2b) + block scan (fused
    // barrier: zeros and s_ws both visible after the scan barrier) ----
    {
        int4* d4 = (int4*)s_diff;
        int4 z; z.x = z.y = z.z = z.w = 0;
        d4[tid] = z;
        d4[tid + 512] = z;
    }
    int texcl;
    {
        int lane = tid & 63, wv = tid >> 6;
        int v = tsum;
        for (int off = 1; off < 64; off <<= 1) {
            int u = __shfl_up(v, off, 64);
            if (lane >= off) v += u;
        }
        if (lane == 63) s_ws[wv] = v;
        __syncthreads();
        int woff = 0;
        for (int w = 0; w < wv; ++w) woff += s_ws[w];
        texcl = woff + v - tsum;
    }

    // ---- Phase 4b: difference-array scatter (+1 start, -1 end) ----
    {
        int o = texcl;
#pragma unroll
        for (int i = 0; i < PER; ++i) {
            if ((use >> i) & 1u) {
                float buf = bsum[i];
                int nf = (int)ceilf(buf / MSSF) - 1; if (nf < 0) nf = 0;
                float rem = buf - (float)nf * MSSF;
                if (nf > 0) {
                    if (o < S_LEN) atomicAdd(&s_diff[o], 1);
                    int e2 = o + nf;
                    if (e2 < S_LEN) atomicAdd(&s_diff[e2], -1);  // OOB drop
                }
                o += nf + (rem > 0.0f ? 1 : 0);
            }
        }
    }
    __syncthreads();

    // ---- Phase 4c: block inclusive scan of diff -> cover writeback ----
    {
        int4 a = *(int4*)&s_diff[sb];
        int4 b = *(int4*)&s_diff[sb + 4];
        int v0 = a.x,      v1 = v0 + a.y, v2 = v1 + a.z, v3 = v2 + a.w;
        int v4 = v3 + b.x, v5 = v4 + b.y, v6 = v5 + b.z, v7 = v6 + b.w;
        int T = v7;
        int lane = tid & 63, wv = tid >> 6;
        int sc = T;
        for (int off = 1; off < 64; off <<= 1) {
            int u = __shfl_up(sc, off, 64);
            if (lane >= off) sc += u;
        }
        if (lane == 63) s_ws[wv] = sc;
        __syncthreads();
        int basev = 0;
        for (int w = 0; w < wv; ++w) basev += s_ws[w];
        basev += sc - T;                   // exclusive prefix for slot sb
        float4 fa, fb;
        fa.x = (basev + v0 > 0) ? MSSF : 0.0f;
        fa.y = (basev + v1 > 0) ? MSSF : 0.0f;
        fa.z = (basev + v2 > 0) ? MSSF : 0.0f;
        fa.w = (basev + v3 > 0) ? MSSF : 0.0f;
        fb.x = (basev + v4 > 0) ? MSSF : 0.0f;
        fb.y = (basev + v5 > 0) ? MSSF : 0.0f;
        fb.z = (basev + v6 > 0) ? MSSF : 0.0f;
        fb.w = (basev + v7 > 0) ? MSSF : 0.0f;
        *(float4*)&s_out[sb]     = fa;     // in-place over own diff slots: safe
        *(float4*)&s_out[sb + 4] = fb;
    }
    __syncthreads();

    // ---- Phase 4d: remainder scatter (rem slot never MSS-covered) ----
    {
        int o = texcl;
#pragma unroll
        for (int i = 0; i < PER; ++i) {
            if ((use >> i) & 1u) {
                float buf = bsum[i];
                int nf = (int)ceilf(buf / MSSF) - 1; if (nf < 0) nf = 0;
                float rem = buf - (float)nf * MSSF;
                int rp = o + nf;
                if (rem > 0.0f && rp < S_LEN) s_out[rp] = rem;
                o += nf + (rem > 0.0f ? 1 : 0);
            }
        }
    }
    __syncthreads();

    // ---- Phase 4e: coalesced store ----
    {
        float4* po4 = (float4*)(gout + rowoff);
        const float4* so4 = (const float4*)s_out;
        po4[tid]       = so4[tid];
        po4[tid + 512] = so4[tid + 512];
    }
}

extern "C" void kernel_launch(void* const* d_in, const int* in_sizes, int n_in,
                              void* d_out, int out_size, void* d_ws, size_t ws_size,
                              hipStream_t stream) {
    const float* x      = (const float*)d_in[0];
    const float* delays = (const float*)d_in[1];
    const float* rtts   = (const float*)d_in[2];
    float* out = (float*)d_out;
    int rows = in_sizes[0] / S_LEN;   // B = 2048
    traffic_kernel<<<rows, BLOCK, 0, stream>>>(x, delays, rtts, out);
}